// Round 10
// baseline (116.213 us; speedup 1.0000x reference)
//
#include <hip/hip_runtime.h>
#include <hip/hip_bf16.h>
#include <math.h>

#define BATCH      2048
#define IN_DIM     784
#define HIDDEN     512
#define STYLE      128
#define NUM_LABELS 10
#define FC1_STRIDE ((IN_DIM + 1) * HIDDEN)   // 785*512
#define FC2_STRIDE ((HIDDEN + 1) * STYLE)    // 513*128
#define KP1        832                        // IN_DIM padded to mult of 64
#define TB         64
#define BK         64
#define MAX_TILES  48    // >= max possible sum(ceil(c_L/64)) = 41

// ws: h1b only ([2048][512] bf16, permuted rows)
#define WS_NEED  ((size_t)BATCH * HIDDEN * 2)

typedef short short8  __attribute__((ext_vector_type(8)));
typedef float float4e __attribute__((ext_vector_type(4)));

__device__ __forceinline__ ushort f2b(float v) {
    __hip_bfloat16 h = __float2bfloat16(v);
    return *reinterpret_cast<ushort*>(&h);
}

// Per-block meta recompute: every block derives the identical label-sort
// deterministically (histogram -> tile lookup -> stable block scan), so the
// two GEMM kernels agree on the permutation with NO shared metadata.
// Returns false if bt has no tile. Fills rowsS[64] (-1 pad) and outputs
// L/pstart/nrows.
__device__ __forceinline__ bool block_meta(const int* __restrict__ m, int bt,
                                           int* cntS, int* scanS, int* rowsS,
                                           int& L, int& pstart, int& nrows) {
    const int tid = threadIdx.x;
    int mloc[8];
#pragma unroll
    for (int i = 0; i < 8; ++i) mloc[i] = m[tid * 8 + i];

    if (tid < NUM_LABELS) cntS[tid] = 0;
    __syncthreads();
    // histogram via ballot: no LDS-atomic contention
#pragma unroll
    for (int i = 0; i < 8; ++i) {
        const int v = mloc[i];
#pragma unroll
        for (int Li = 0; Li < NUM_LABELS; ++Li) {
            unsigned long long bal = __ballot(v == Li);
            if ((tid & 63) == 0) atomicAdd(&cntS[Li], (int)__popcll(bal));
        }
    }
    __syncthreads();

    // uniform tile lookup: bt -> (L, t, pstart, nrows)
    L = -1; pstart = 0; nrows = 0; int t = 0;
    {
        int off = 0, idx = 0;
        for (int Li = 0; Li < NUM_LABELS; ++Li) {
            const int c = cntS[Li];
            const int nt = (c + TB - 1) >> 6;
            if (L < 0 && bt >= idx && bt < idx + nt) {
                L = Li; t = bt - idx;
                pstart = off + t * TB;
                nrows = min(TB, c - t * TB);
            }
            idx += nt; off += c;
        }
    }
    if (L < 0) return false;

    // stable compaction of label-L rows; keep ranks [t*64, t*64+64)
    int loc = 0;
#pragma unroll
    for (int i = 0; i < 8; ++i) loc += (mloc[i] == L);
    scanS[tid] = loc;
    __syncthreads();
    for (int s = 1; s < 256; s <<= 1) {
        int v = scanS[tid];
        int u = (tid >= s) ? scanS[tid - s] : 0;
        __syncthreads();
        scanS[tid] = v + u;
        __syncthreads();
    }
    const int base = (tid > 0) ? scanS[tid - 1] : 0;
    if (tid < TB) rowsS[tid] = -1;
    __syncthreads();
    const int lo = t * TB, hi = lo + TB;
    int r = base;
#pragma unroll
    for (int i = 0; i < 8; ++i) {
        if (mloc[i] == L) {
            if (r >= lo && r < hi) rowsS[r - lo] = tid * 8 + i;
            ++r;
        }
    }
    __syncthreads();
    return true;
}

// ---------- fc1: h1b = relu(x . W1 + b1); inline x-cvt + inline W1 transpose-cvt ----------
__launch_bounds__(256)
__global__ void k_fc1m(const float* __restrict__ x, const int* __restrict__ m,
                       const float* __restrict__ fc1t, ushort* __restrict__ h1b) {
    __shared__ int cntS[NUM_LABELS], scanS[256], rowsS[TB];
    __shared__ __align__(16) ushort As[2][64][72];
    __shared__ __align__(16) ushort Bs[2][64][72];

    int L, pstart, nrows;
    if (!block_meta(m, blockIdx.x, cntS, scanS, rowsS, L, pstart, nrows)) return;
    const int col0 = blockIdx.y * 64;
    const float* __restrict__ W = fc1t + (size_t)L * FC1_STRIDE;  // [k][n], n-stride 512

    const int tid = threadIdx.x;
    const int sr = tid >> 2, sc = tid & 3;         // A staging: row, 16-float chunk
    const int kq = tid >> 4, nq = tid & 15;        // B staging: 4k x 4n patch
    const int lane = tid & 63, wv = tid >> 6;
    const int qd = lane >> 4, ln16 = lane & 15;

    const int arow = rowsS[sr];
    const float* __restrict__ xr = x + (size_t)(arow < 0 ? 0 : arow) * IN_DIM;

    float4e acc[4] = {};
    float4 a0, a1, a2, a3;
    float4 bw[4];

    // helper lambdas (compiled inline)
    auto loadA = [&](int k0) {
        const int ka = k0 + sc * 16;
        a0 = make_float4(0.f,0.f,0.f,0.f); a1 = a0; a2 = a0; a3 = a0;
        if (arow >= 0) {
            if (ka      < IN_DIM) a0 = *(const float4*)(xr + ka);
            if (ka + 4  < IN_DIM) a1 = *(const float4*)(xr + ka + 4);
            if (ka + 8  < IN_DIM) a2 = *(const float4*)(xr + ka + 8);
            if (ka + 12 < IN_DIM) a3 = *(const float4*)(xr + ka + 12);
        }
    };
    auto loadB = [&](int k0) {
#pragma unroll
        for (int kk = 0; kk < 4; ++kk) {
            const int gk = k0 + kq * 4 + kk;
            bw[kk] = (gk < IN_DIM) ? *(const float4*)(W + (size_t)gk * HIDDEN + col0 + nq * 4)
                                   : make_float4(0.f,0.f,0.f,0.f);
        }
    };
    auto storeA = [&](int p) {
        ushort av[16];
        av[0]=f2b(a0.x); av[1]=f2b(a0.y); av[2]=f2b(a0.z); av[3]=f2b(a0.w);
        av[4]=f2b(a1.x); av[5]=f2b(a1.y); av[6]=f2b(a1.z); av[7]=f2b(a1.w);
        av[8]=f2b(a2.x); av[9]=f2b(a2.y); av[10]=f2b(a2.z); av[11]=f2b(a2.w);
        av[12]=f2b(a3.x); av[13]=f2b(a3.y); av[14]=f2b(a3.z); av[15]=f2b(a3.w);
        *(uint4*)&As[p][sr][sc * 16 + 0] = *(const uint4*)&av[0];
        *(uint4*)&As[p][sr][sc * 16 + 8] = *(const uint4*)&av[8];
    };
    auto storeB = [&](int p) {     // transpose: Bs[n][k] <- bw[kk].nn
#pragma unroll
        for (int nn = 0; nn < 4; ++nn) {
            ushort kv[4] = { f2b((&bw[0].x)[nn]), f2b((&bw[1].x)[nn]),
                             f2b((&bw[2].x)[nn]), f2b((&bw[3].x)[nn]) };
            *(uint2*)&Bs[p][nq * 4 + nn][kq * 4] = *(const uint2*)kv;
        }
    };

    loadA(0); loadB(0);
    storeA(0); storeB(0);
    loadA(BK); loadB(BK);

    int p = 0;
    for (int k0 = 0; k0 < KP1; k0 += BK) {
        __syncthreads();
        if (k0 + BK < KP1) { storeA(1 - p); storeB(1 - p); }
        if (k0 + 2 * BK < KP1) { loadA(k0 + 2 * BK); loadB(k0 + 2 * BK); }
#pragma unroll
        for (int s = 0; s < 2; ++s) {
            short8 af = *(const short8*)&As[p][wv * 16 + ln16][s * 32 + qd * 8];
#pragma unroll
            for (int nt = 0; nt < 4; ++nt) {
                short8 bf = *(const short8*)&Bs[p][nt * 16 + ln16][s * 32 + qd * 8];
                acc[nt] = __builtin_amdgcn_mfma_f32_16x16x32_bf16(af, bf, acc[nt], 0, 0, 0);
            }
        }
        p ^= 1;
    }

    const float* __restrict__ bias = W + (size_t)IN_DIM * HIDDEN + col0;
#pragma unroll
    for (int nt = 0; nt < 4; ++nt) {
        const int c = nt * 16 + ln16;
        const float bs = bias[c];
#pragma unroll
        for (int i = 0; i < 4; ++i) {
            const int r = wv * 16 + qd * 4 + i;
            if (r < nrows)
                h1b[(size_t)(pstart + r) * HIDDEN + col0 + c] = f2b(fmaxf(acc[nt][i] + bs, 0.f));
        }
    }
}

// ---------- fc2: out = sigmoid(h1 . W2 + b2); inline W2 transpose-cvt ----------
__launch_bounds__(256)
__global__ void k_fc2m(const ushort* __restrict__ h1b, const int* __restrict__ m,
                       const float* __restrict__ fc2t, float* __restrict__ out) {
    __shared__ int cntS[NUM_LABELS], scanS[256], rowsS[TB];
    __shared__ __align__(16) ushort As[2][64][72];
    __shared__ __align__(16) ushort Bs[2][64][72];

    int L, pstart, nrows;
    if (!block_meta(m, blockIdx.x, cntS, scanS, rowsS, L, pstart, nrows)) return;
    const int col0 = blockIdx.y * 64;
    const float* __restrict__ W = fc2t + (size_t)L * FC2_STRIDE;  // [k][n], n-stride 128

    const int tid = threadIdx.x;
    const int sr = tid >> 2, sc = tid & 3;
    const int kq = tid >> 4, nq = tid & 15;
    const int lane = tid & 63, wv = tid >> 6;
    const int qd = lane >> 4, ln16 = lane & 15;

    const bool aval = (sr < nrows);
    const uint4* __restrict__ agp = (const uint4*)(h1b + (size_t)(pstart + (aval ? sr : 0)) * HIDDEN);

    float4e acc[4] = {};
    uint4 a0, a1;
    float4 bw[4];

    auto loadA = [&](int k0) {
        const int base = (k0 >> 3) + sc * 2;
        a0 = make_uint4(0u,0u,0u,0u); a1 = a0;
        if (aval) { a0 = agp[base]; a1 = agp[base + 1]; }
    };
    auto loadB = [&](int k0) {
#pragma unroll
        for (int kk = 0; kk < 4; ++kk) {
            const int gk = k0 + kq * 4 + kk;
            bw[kk] = *(const float4*)(W + (size_t)gk * STYLE + col0 + nq * 4);
        }
    };
    auto storeA = [&](int p) {
        *(uint4*)&As[p][sr][sc * 16 + 0] = a0;
        *(uint4*)&As[p][sr][sc * 16 + 8] = a1;
    };
    auto storeB = [&](int p) {
#pragma unroll
        for (int nn = 0; nn < 4; ++nn) {
            ushort kv[4] = { f2b((&bw[0].x)[nn]), f2b((&bw[1].x)[nn]),
                             f2b((&bw[2].x)[nn]), f2b((&bw[3].x)[nn]) };
            *(uint2*)&Bs[p][nq * 4 + nn][kq * 4] = *(const uint2*)kv;
        }
    };

    loadA(0); loadB(0);
    storeA(0); storeB(0);
    loadA(BK); loadB(BK);

    int p = 0;
    for (int k0 = 0; k0 < HIDDEN; k0 += BK) {
        __syncthreads();
        if (k0 + BK < HIDDEN) { storeA(1 - p); storeB(1 - p); }
        if (k0 + 2 * BK < HIDDEN) { loadA(k0 + 2 * BK); loadB(k0 + 2 * BK); }
#pragma unroll
        for (int s = 0; s < 2; ++s) {
            short8 af = *(const short8*)&As[p][wv * 16 + ln16][s * 32 + qd * 8];
#pragma unroll
            for (int nt = 0; nt < 4; ++nt) {
                short8 bf = *(const short8*)&Bs[p][nt * 16 + ln16][s * 32 + qd * 8];
                acc[nt] = __builtin_amdgcn_mfma_f32_16x16x32_bf16(af, bf, acc[nt], 0, 0, 0);
            }
        }
        p ^= 1;
    }

    const float* __restrict__ bias = W + (size_t)HIDDEN * STYLE + col0;
#pragma unroll
    for (int nt = 0; nt < 4; ++nt) {
        const int c = nt * 16 + ln16;
        const float bs = bias[c];
#pragma unroll
        for (int i = 0; i < 4; ++i) {
            const int r = wv * 16 + qd * 4 + i;
            if (r < nrows) {
                const int orow = rowsS[r];
                out[(size_t)orow * STYLE + col0 + c] = 1.f / (1.f + __expf(-(acc[nt][i] + bs)));
            }
        }
    }
}

// ---------- fallback (ws too small): fused per-row, slow but correct ----------
__launch_bounds__(256)
__global__ void k_naive(const float* __restrict__ x, const int* __restrict__ m,
                        const float* __restrict__ fc1t, const float* __restrict__ fc2t,
                        float* __restrict__ out) {
    __shared__ float xs[IN_DIM];
    __shared__ float h1[HIDDEN];
    const int b = blockIdx.x, tid = threadIdx.x, L = m[b];
    for (int k = tid; k < IN_DIM; k += 256) xs[k] = x[(size_t)b * IN_DIM + k];
    __syncthreads();
    const float* __restrict__ W1 = fc1t + (size_t)L * FC1_STRIDE;
    for (int j = tid; j < HIDDEN; j += 256) {
        float acc = W1[(size_t)IN_DIM * HIDDEN + j];
        for (int k = 0; k < IN_DIM; ++k) acc = fmaf(xs[k], W1[(size_t)k * HIDDEN + j], acc);
        h1[j] = fmaxf(acc, 0.f);
    }
    __syncthreads();
    const float* __restrict__ W2 = fc2t + (size_t)L * FC2_STRIDE;
    for (int j = tid; j < STYLE; j += 256) {
        float acc = W2[(size_t)HIDDEN * STYLE + j];
        for (int k = 0; k < HIDDEN; ++k) acc = fmaf(h1[k], W2[(size_t)k * STYLE + j], acc);
        out[(size_t)b * STYLE + j] = 1.f / (1.f + __expf(-acc));
    }
}

extern "C" void kernel_launch(void* const* d_in, const int* in_sizes, int n_in,
                              void* d_out, int out_size, void* d_ws, size_t ws_size,
                              hipStream_t stream) {
    const float* x    = (const float*)d_in[0];
    const int*   m    = (const int*)d_in[1];
    const float* fc1t = (const float*)d_in[2];
    const float* fc2t = (const float*)d_in[3];
    float* out = (float*)d_out;

    if (ws_size >= WS_NEED) {
        ushort* h1b = (ushort*)d_ws;
        k_fc1m<<<dim3(MAX_TILES, HIDDEN / 64), 256, 0, stream>>>(x, m, fc1t, h1b);
        k_fc2m<<<dim3(MAX_TILES, STYLE / 64), 256, 0, stream>>>(h1b, m, fc2t, out);
    } else {
        k_naive<<<BATCH, 256, 0, stream>>>(x, m, fc1t, fc2t, out);
    }
}

// Round 11
// 102.312 us; speedup vs baseline: 1.1359x; 1.1359x over previous
//
#include <hip/hip_runtime.h>
#include <hip/hip_bf16.h>
#include <math.h>

#define BATCH      2048
#define IN_DIM     784
#define HIDDEN     512
#define STYLE      128
#define NUM_LABELS 10
#define FC1_STRIDE ((IN_DIM + 1) * HIDDEN)   // 785*512
#define FC2_STRIDE ((HIDDEN + 1) * STYLE)    // 513*128
#define KP1        832                        // IN_DIM padded to mult of 64
#define TB         64
#define BK         64
#define MAX_TILES  48    // >= max possible sum(ceil(c_L/64)) = 41

// ---- meta (int) layout at d_ws byte 0 ----
#define META_NTILES 31
#define META_TILES  32     // 3 ints per tile: label,pstart,nrows
#define META_PERM   176

// ---- bf16 workspace layout (byte offsets) ----
#define W1B_OFF  16384ULL                               // [10][512][832] bf16 ([L][n][k])
#define W2B_OFF  (W1B_OFF + 10ULL*HIDDEN*KP1*2)         // [10][128][512] bf16 ([L][n][k])
#define H1B_OFF  (W2B_OFF + 10ULL*STYLE*HIDDEN*2)       // [2048][512] bf16 (permuted rows)
#define BF16_NEED (H1B_OFF + (size_t)BATCH*HIDDEN*2)    // ~11.9 MB

// 64x64 transpose tiles (vectorized prep)
#define W1T_K  (KP1/64)      // 13
#define W1T_N  (HIDDEN/64)   // 8
#define W2T_K  (HIDDEN/64)   // 8
#define W2T_N  (STYLE/64)    // 2
#define W1_TBLK (W1T_K*W1T_N*NUM_LABELS)   // 1040
#define W2_TBLK (W2T_K*W2T_N*NUM_LABELS)   // 160

typedef short short8  __attribute__((ext_vector_type(8)));
typedef float float4e __attribute__((ext_vector_type(4)));

__device__ __forceinline__ ushort f2b(float v) {
    __hip_bfloat16 h = __float2bfloat16(v);
    return *reinterpret_cast<ushort*>(&h);
}

// ---------- prep: block 0 = meta; rest = 64x64 vectorized weight transpose+convert ----------
__global__ void k_prep(const int* __restrict__ m, const float* __restrict__ fc1t,
                       const float* __restrict__ fc2t, int* __restrict__ meta,
                       ushort* __restrict__ w1b, ushort* __restrict__ w2b) {
    const int tid = threadIdx.x;
    int bid = blockIdx.x;

    __shared__ int cnt[NUM_LABELS], curs[NUM_LABELS], offs[NUM_LABELS + 1];
    __shared__ int permS[BATCH];
    __shared__ float tile[64][68];   // 68 stride: 16B-aligned float4 stores; 4-way read alias ok

    if (bid == 0) {
        if (tid < NUM_LABELS) { cnt[tid] = 0; curs[tid] = 0; }
        __syncthreads();
        for (int b = tid; b < BATCH; b += 256) atomicAdd(&cnt[m[b]], 1);
        __syncthreads();
        if (tid == 0) {
            int off = 0;
            for (int L = 0; L < NUM_LABELS; ++L) { offs[L] = off; off += cnt[L]; }
            offs[NUM_LABELS] = off;
        }
        __syncthreads();
        for (int b = tid; b < BATCH; b += 256) {
            int L = m[b];
            int r = atomicAdd(&curs[L], 1);
            permS[offs[L] + r] = b;
        }
        __syncthreads();
        for (int i = tid; i < BATCH; i += 256) meta[META_PERM + i] = permS[i];
        if (tid == 0) {
            int idx = 0;
            for (int L = 0; L < NUM_LABELS; ++L) {
                int c = cnt[L], off = offs[L];
                for (int t = 0; t < c; t += TB) {
                    meta[META_TILES + idx * 3 + 0] = L;
                    meta[META_TILES + idx * 3 + 1] = off + t;
                    meta[META_TILES + idx * 3 + 2] = min(TB, c - t);
                    ++idx;
                }
            }
            meta[META_NTILES] = idx;
        }
        return;
    }

    bid -= 1;
    const float* src; ushort* dst; int Kv, Kp, N, kb, nb, L; size_t sL, dL;
    if (bid < W1_TBLK) {
        kb = bid % W1T_K; nb = (bid / W1T_K) % W1T_N; L = bid / (W1T_K * W1T_N);
        src = fc1t; dst = w1b; Kv = IN_DIM; Kp = KP1; N = HIDDEN;
        sL = FC1_STRIDE; dL = (size_t)HIDDEN * KP1;
    } else {
        int q2 = bid - W1_TBLK;
        kb = q2 % W2T_K; nb = (q2 / W2T_K) % W2T_N; L = q2 / (W2T_K * W2T_N);
        src = fc2t; dst = w2b; Kv = HIDDEN; Kp = HIDDEN; N = STYLE;
        sL = FC2_STRIDE; dL = (size_t)STYLE * HIDDEN;
    }
    const int k0 = kb * 64, n0 = nb * 64;
    const int r = tid >> 2, q = tid & 3;           // load: row r, 16-col chunk q
    const int gk = k0 + r;
#pragma unroll
    for (int j = 0; j < 4; ++j) {
        float4 v = make_float4(0.f, 0.f, 0.f, 0.f);
        if (gk < Kv) v = *(const float4*)(src + (size_t)L * sL + (size_t)gk * N + n0 + q * 16 + j * 4);
        *(float4*)&tile[r][q * 16 + j * 4] = v;
    }
    __syncthreads();
    const int n = tid >> 2;                        // store: dst row n0+n, 16-k chunk q
    ushort kv[16];
#pragma unroll
    for (int j = 0; j < 16; ++j) kv[j] = f2b(tile[q * 16 + j][n]);
    ushort* drow = dst + (size_t)L * dL + (size_t)(n0 + n) * Kp + k0 + q * 16;
    *(uint4*)(drow + 0) = *(const uint4*)&kv[0];
    *(uint4*)(drow + 8) = *(const uint4*)&kv[8];
}

// ---------- fc1: bf16 MFMA, BK=64, LDS double-buffer (round-9 exact) ----------
__launch_bounds__(256)
__global__ void k_fc1m(const float* __restrict__ x, const ushort* __restrict__ w1b,
                       const float* __restrict__ fc1t, const int* __restrict__ meta,
                       ushort* __restrict__ h1b) {
    const int t = blockIdx.x;
    if (t >= meta[META_NTILES]) return;
    const int L      = meta[META_TILES + 3 * t + 0];
    const int pstart = meta[META_TILES + 3 * t + 1];
    const int nrows  = meta[META_TILES + 3 * t + 2];
    const int col0   = blockIdx.y * 64;
    const ushort* __restrict__ W = w1b + (size_t)L * HIDDEN * KP1 + (size_t)col0 * KP1;

    __shared__ int rows[TB];
    __shared__ __align__(16) ushort As[2][64][72];
    __shared__ __align__(16) ushort Bs[2][64][72];

    const int tid = threadIdx.x;
    if (tid < TB) rows[tid] = (tid < nrows) ? meta[META_PERM + pstart + tid] : -1;
    __syncthreads();

    const int sr = tid >> 2, sc = tid & 3;
    const int lane = tid & 63, wv = tid >> 6;
    const int qd = lane >> 4, ln16 = lane & 15;

    const int arow = rows[sr];
    const float* __restrict__ xr = x + (size_t)(arow < 0 ? 0 : arow) * IN_DIM;
    const uint4* __restrict__ bgp = (const uint4*)(W + (size_t)sr * KP1);

    float4e acc[4] = {};
    float4 a0, a1, a2, a3;
    uint4 b0, b1;

    {
        const int ka = sc * 16;
        a0 = make_float4(0.f,0.f,0.f,0.f); a1 = a0; a2 = a0; a3 = a0;
        if (arow >= 0) {
            if (ka      < IN_DIM) a0 = *(const float4*)(xr + ka);
            if (ka + 4  < IN_DIM) a1 = *(const float4*)(xr + ka + 4);
            if (ka + 8  < IN_DIM) a2 = *(const float4*)(xr + ka + 8);
            if (ka + 12 < IN_DIM) a3 = *(const float4*)(xr + ka + 12);
        }
        b0 = bgp[sc * 2 + 0];
        b1 = bgp[sc * 2 + 1];
        ushort av[16];
        av[0]=f2b(a0.x); av[1]=f2b(a0.y); av[2]=f2b(a0.z); av[3]=f2b(a0.w);
        av[4]=f2b(a1.x); av[5]=f2b(a1.y); av[6]=f2b(a1.z); av[7]=f2b(a1.w);
        av[8]=f2b(a2.x); av[9]=f2b(a2.y); av[10]=f2b(a2.z); av[11]=f2b(a2.w);
        av[12]=f2b(a3.x); av[13]=f2b(a3.y); av[14]=f2b(a3.z); av[15]=f2b(a3.w);
        *(uint4*)&As[0][sr][sc * 16 + 0] = *(const uint4*)&av[0];
        *(uint4*)&As[0][sr][sc * 16 + 8] = *(const uint4*)&av[8];
        *(uint4*)&Bs[0][sr][sc * 16 + 0] = b0;
        *(uint4*)&Bs[0][sr][sc * 16 + 8] = b1;
    }
    {
        const int ka = BK + sc * 16;
        a0 = make_float4(0.f,0.f,0.f,0.f); a1 = a0; a2 = a0; a3 = a0;
        if (arow >= 0) {
            if (ka      < IN_DIM) a0 = *(const float4*)(xr + ka);
            if (ka + 4  < IN_DIM) a1 = *(const float4*)(xr + ka + 4);
            if (ka + 8  < IN_DIM) a2 = *(const float4*)(xr + ka + 8);
            if (ka + 12 < IN_DIM) a3 = *(const float4*)(xr + ka + 12);
        }
        b0 = bgp[(BK >> 3) + sc * 2 + 0];
        b1 = bgp[(BK >> 3) + sc * 2 + 1];
    }

    int p = 0;
    for (int k0 = 0; k0 < KP1; k0 += BK) {
        __syncthreads();
        if (k0 + BK < KP1) {
            ushort av[16];
            av[0]=f2b(a0.x); av[1]=f2b(a0.y); av[2]=f2b(a0.z); av[3]=f2b(a0.w);
            av[4]=f2b(a1.x); av[5]=f2b(a1.y); av[6]=f2b(a1.z); av[7]=f2b(a1.w);
            av[8]=f2b(a2.x); av[9]=f2b(a2.y); av[10]=f2b(a2.z); av[11]=f2b(a2.w);
            av[12]=f2b(a3.x); av[13]=f2b(a3.y); av[14]=f2b(a3.z); av[15]=f2b(a3.w);
            *(uint4*)&As[1-p][sr][sc * 16 + 0] = *(const uint4*)&av[0];
            *(uint4*)&As[1-p][sr][sc * 16 + 8] = *(const uint4*)&av[8];
            *(uint4*)&Bs[1-p][sr][sc * 16 + 0] = b0;
            *(uint4*)&Bs[1-p][sr][sc * 16 + 8] = b1;
        }
        if (k0 + 2*BK < KP1) {
            const int ka = k0 + 2*BK + sc * 16;
            a0 = make_float4(0.f,0.f,0.f,0.f); a1 = a0; a2 = a0; a3 = a0;
            if (arow >= 0) {
                if (ka      < IN_DIM) a0 = *(const float4*)(xr + ka);
                if (ka + 4  < IN_DIM) a1 = *(const float4*)(xr + ka + 4);
                if (ka + 8  < IN_DIM) a2 = *(const float4*)(xr + ka + 8);
                if (ka + 12 < IN_DIM) a3 = *(const float4*)(xr + ka + 12);
            }
            b0 = bgp[((k0 + 2*BK) >> 3) + sc * 2 + 0];
            b1 = bgp[((k0 + 2*BK) >> 3) + sc * 2 + 1];
        }
#pragma unroll
        for (int s = 0; s < 2; ++s) {
            short8 af = *(const short8*)&As[p][wv * 16 + ln16][s * 32 + qd * 8];
#pragma unroll
            for (int nt = 0; nt < 4; ++nt) {
                short8 bf = *(const short8*)&Bs[p][nt * 16 + ln16][s * 32 + qd * 8];
                acc[nt] = __builtin_amdgcn_mfma_f32_16x16x32_bf16(af, bf, acc[nt], 0, 0, 0);
            }
        }
        p ^= 1;
    }

    const float* __restrict__ bias = fc1t + (size_t)L * FC1_STRIDE + (size_t)IN_DIM * HIDDEN + col0;
#pragma unroll
    for (int nt = 0; nt < 4; ++nt) {
        const int c = nt * 16 + ln16;
        const float bs = bias[c];
#pragma unroll
        for (int i = 0; i < 4; ++i) {
            const int r = wv * 16 + qd * 4 + i;
            if (r < nrows)
                h1b[(size_t)(pstart + r) * HIDDEN + col0 + c] = f2b(fmaxf(acc[nt][i] + bs, 0.f));
        }
    }
}

// ---------- fc2: bf16 MFMA, BK=64, LDS double-buffer (round-9 exact) ----------
__launch_bounds__(256)
__global__ void k_fc2m(const ushort* __restrict__ h1b, const ushort* __restrict__ w2b,
                       const float* __restrict__ fc2t, const int* __restrict__ meta,
                       float* __restrict__ out) {
    const int t = blockIdx.x;
    if (t >= meta[META_NTILES]) return;
    const int L      = meta[META_TILES + 3 * t + 0];
    const int pstart = meta[META_TILES + 3 * t + 1];
    const int nrows  = meta[META_TILES + 3 * t + 2];
    const int col0   = blockIdx.y * 64;
    const ushort* __restrict__ W = w2b + (size_t)L * STYLE * HIDDEN + (size_t)col0 * HIDDEN;

    __shared__ int rows[TB];
    __shared__ __align__(16) ushort As[2][64][72];
    __shared__ __align__(16) ushort Bs[2][64][72];

    const int tid = threadIdx.x;
    if (tid < TB) rows[tid] = (tid < nrows) ? meta[META_PERM + pstart + tid] : -1;
    __syncthreads();

    const int sr = tid >> 2, sc = tid & 3;
    const int lane = tid & 63, wv = tid >> 6;
    const int qd = lane >> 4, ln16 = lane & 15;

    const bool aval = (sr < nrows);
    const uint4* __restrict__ agp = (const uint4*)(h1b + (size_t)(pstart + (aval ? sr : 0)) * HIDDEN);
    const uint4* __restrict__ bgp = (const uint4*)(W + (size_t)sr * HIDDEN);

    float4e acc[4] = {};
    uint4 a0, a1, b0, b1;

    a0 = make_uint4(0u,0u,0u,0u); a1 = a0;
    if (aval) { a0 = agp[sc * 2 + 0]; a1 = agp[sc * 2 + 1]; }
    b0 = bgp[sc * 2 + 0];
    b1 = bgp[sc * 2 + 1];
    *(uint4*)&As[0][sr][sc * 16 + 0] = a0;
    *(uint4*)&As[0][sr][sc * 16 + 8] = a1;
    *(uint4*)&Bs[0][sr][sc * 16 + 0] = b0;
    *(uint4*)&Bs[0][sr][sc * 16 + 8] = b1;
    {
        const int base = (BK >> 3) + sc * 2;
        a0 = make_uint4(0u,0u,0u,0u); a1 = a0;
        if (aval) { a0 = agp[base]; a1 = agp[base + 1]; }
        b0 = bgp[base];
        b1 = bgp[base + 1];
    }

    int p = 0;
    for (int k0 = 0; k0 < HIDDEN; k0 += BK) {
        __syncthreads();
        if (k0 + BK < HIDDEN) {
            *(uint4*)&As[1-p][sr][sc * 16 + 0] = a0;
            *(uint4*)&As[1-p][sr][sc * 16 + 8] = a1;
            *(uint4*)&Bs[1-p][sr][sc * 16 + 0] = b0;
            *(uint4*)&Bs[1-p][sr][sc * 16 + 8] = b1;
        }
        if (k0 + 2*BK < HIDDEN) {
            const int base = ((k0 + 2*BK) >> 3) + sc * 2;
            a0 = make_uint4(0u,0u,0u,0u); a1 = a0;
            if (aval) { a0 = agp[base]; a1 = agp[base + 1]; }
            b0 = bgp[base];
            b1 = bgp[base + 1];
        }
#pragma unroll
        for (int s = 0; s < 2; ++s) {
            short8 af = *(const short8*)&As[p][wv * 16 + ln16][s * 32 + qd * 8];
#pragma unroll
            for (int nt = 0; nt < 4; ++nt) {
                short8 bf = *(const short8*)&Bs[p][nt * 16 + ln16][s * 32 + qd * 8];
                acc[nt] = __builtin_amdgcn_mfma_f32_16x16x32_bf16(af, bf, acc[nt], 0, 0, 0);
            }
        }
        p ^= 1;
    }

    const float* __restrict__ bias = fc2t + (size_t)L * FC2_STRIDE + (size_t)HIDDEN * STYLE + col0;
#pragma unroll
    for (int nt = 0; nt < 4; ++nt) {
        const int c = nt * 16 + ln16;
        const float bs = bias[c];
#pragma unroll
        for (int i = 0; i < 4; ++i) {
            const int r = wv * 16 + qd * 4 + i;
            if (r < nrows) {
                const int orow = rows[r];
                out[(size_t)orow * STYLE + col0 + c] = 1.f / (1.f + __expf(-(acc[nt][i] + bs)));
            }
        }
    }
}

// ---------- fallback (ws too small): fused per-row, slow but correct ----------
__launch_bounds__(256)
__global__ void k_naive(const float* __restrict__ x, const int* __restrict__ m,
                        const float* __restrict__ fc1t, const float* __restrict__ fc2t,
                        float* __restrict__ out) {
    __shared__ float xs[IN_DIM];
    __shared__ float h1[HIDDEN];
    const int b = blockIdx.x, tid = threadIdx.x, L = m[b];
    for (int k = tid; k < IN_DIM; k += 256) xs[k] = x[(size_t)b * IN_DIM + k];
    __syncthreads();
    const float* __restrict__ W1 = fc1t + (size_t)L * FC1_STRIDE;
    for (int j = tid; j < HIDDEN; j += 256) {
        float acc = W1[(size_t)IN_DIM * HIDDEN + j];
        for (int k = 0; k < IN_DIM; ++k) acc = fmaf(xs[k], W1[(size_t)k * HIDDEN + j], acc);
        h1[j] = fmaxf(acc, 0.f);
    }
    __syncthreads();
    const float* __restrict__ W2 = fc2t + (size_t)L * FC2_STRIDE;
    for (int j = tid; j < STYLE; j += 256) {
        float acc = W2[(size_t)HIDDEN * STYLE + j];
        for (int k = 0; k < HIDDEN; ++k) acc = fmaf(h1[k], W2[(size_t)k * STYLE + j], acc);
        out[(size_t)b * STYLE + j] = 1.f / (1.f + __expf(-acc));
    }
}

extern "C" void kernel_launch(void* const* d_in, const int* in_sizes, int n_in,
                              void* d_out, int out_size, void* d_ws, size_t ws_size,
                              hipStream_t stream) {
    const float* x    = (const float*)d_in[0];
    const int*   m    = (const int*)d_in[1];
    const float* fc1t = (const float*)d_in[2];
    const float* fc2t = (const float*)d_in[3];
    float* out = (float*)d_out;

    if (ws_size >= BF16_NEED) {
        int*    meta = (int*)d_ws;
        ushort* w1b  = (ushort*)((char*)d_ws + W1B_OFF);
        ushort* w2b  = (ushort*)((char*)d_ws + W2B_OFF);
        ushort* h1b  = (ushort*)((char*)d_ws + H1B_OFF);

        k_prep<<<1 + W1_TBLK + W2_TBLK, 256, 0, stream>>>(m, fc1t, fc2t, meta, w1b, w2b);
        k_fc1m<<<dim3(MAX_TILES, HIDDEN / 64), 256, 0, stream>>>(x, w1b, fc1t, meta, h1b);
        k_fc2m<<<dim3(MAX_TILES, STYLE / 64), 256, 0, stream>>>(h1b, w2b, fc2t, meta, out);
    } else {
        k_naive<<<BATCH, 256, 0, stream>>>(x, m, fc1t, fc2t, out);
    }
}